// Round 1
// baseline (1555.846 us; speedup 1.0000x reference)
//
#include <hip/hip_runtime.h>
#include <math.h>

#define TT 1024
#define BB 16
#define CC 1024
#define HH 16
#define KK 7
#define PADL 6
#define HK 112  // H*K

// ---------------------------------------------------------------------------
// K1: logits = x @ W^T  (per (t,b) row: 112 outputs = 16 heads x 7 taps),
// then band-masked softmax over the 7 taps -> wsm[t,b,h,k] in workspace.
// Thread layout: tx = tid&15 -> head (owns all 7 taps => thread-local softmax)
//                ty = tid>>4 -> row pair; block covers 32 (t,b) rows.
// grid = (T*B)/32 = 512 blocks, 256 threads.
// ---------------------------------------------------------------------------
__global__ __launch_bounds__(256) void k1_weights(const float* __restrict__ x,
                                                  const float* __restrict__ W,
                                                  float* __restrict__ wsm) {
    const int tid = threadIdx.x;
    const int tx = tid & 15;        // head
    const int ty = tid >> 4;        // 0..15
    const int row0 = blockIdx.x * 32 + ty * 2;   // (t*B + b) flat row

    const float* __restrict__ xr0 = x + (size_t)row0 * CC;
    const float* __restrict__ xr1 = xr0 + CC;
    const float* __restrict__ Wr = W + (size_t)tx * KK * CC;  // 7 rows of W

    float acc0[KK], acc1[KK];
#pragma unroll
    for (int k = 0; k < KK; ++k) { acc0[k] = 0.f; acc1[k] = 0.f; }

    for (int c = 0; c < CC; c += 4) {
        const float4 xv0 = *(const float4*)(xr0 + c);
        const float4 xv1 = *(const float4*)(xr1 + c);
#pragma unroll
        for (int k = 0; k < KK; ++k) {
            const float4 wv = *(const float4*)(Wr + (size_t)k * CC + c);
            acc0[k] += xv0.x * wv.x + xv0.y * wv.y + xv0.z * wv.z + xv0.w * wv.w;
            acc1[k] += xv1.x * wv.x + xv1.y * wv.y + xv1.z * wv.z + xv1.w * wv.w;
        }
    }

#pragma unroll
    for (int i = 0; i < 2; ++i) {
        const float* a = (i == 0) ? acc0 : acc1;
        const int row = row0 + i;
        const int t = row >> 4;                    // row = t*B + b
        const int kmin = (t >= PADL) ? 0 : (PADL - t);

        float m = -INFINITY;
#pragma unroll
        for (int k = 0; k < KK; ++k)
            if (k >= kmin) m = fmaxf(m, a[k]);

        float e[KK];
        float s = 0.f;
#pragma unroll
        for (int k = 0; k < KK; ++k) {
            if (k >= kmin) { e[k] = expf(a[k] - m); s += e[k]; }
            else           { e[k] = 0.f; }
        }
        const float inv = 1.f / s;
        float* __restrict__ wp = wsm + (((size_t)row * HH) + tx) * KK;
#pragma unroll
        for (int k = 0; k < KK; ++k) wp[k] = e[k] * inv;
    }
}

// ---------------------------------------------------------------------------
// K2: write the full dense (B*H, T, T) band matrix in ONE streaming pass.
// One block per (bh, t) row: 256 threads x float4 = 4 KB row. Cols in
// [max(0, t-6), t] take softmax weights, everything else zeros.
// grid = B*H*T = 262144 blocks.
// ---------------------------------------------------------------------------
__global__ __launch_bounds__(256) void k2_dense(const float* __restrict__ wsm,
                                                float* __restrict__ dense) {
    const int rid = blockIdx.x;        // bh*T + t
    const int t = rid & (TT - 1);
    const int bh = rid >> 10;          // T = 1024
    const int b = bh >> 4;
    const int h = bh & 15;

    const int col = threadIdx.x << 2;
    const int lo = t - PADL;           // may be negative

    float4 v = make_float4(0.f, 0.f, 0.f, 0.f);
    // only touch wsm if any of our 4 cols is in the band
    if (col + 3 >= lo && col <= t) {
        const float* __restrict__ wp =
            wsm + ((((size_t)t * BB + b) * HH) + h) * KK;
        float* pv = &v.x;
#pragma unroll
        for (int j = 0; j < 4; ++j) {
            const int cc = col + j;
            if (cc >= lo && cc <= t && cc >= 0) pv[j] = wp[cc - lo];
        }
    }
    *(float4*)(dense + (size_t)rid * TT + col) = v;
}

// ---------------------------------------------------------------------------
// K3: out[t,b,c] = sum_k wsm[t,b,h,k] * x[t+k-6, b, c],  h = c/64.
// One block per (t,b) row, 256 threads x float4 over C.
// grid = T*B = 16384 blocks.
// ---------------------------------------------------------------------------
__global__ __launch_bounds__(256) void k3_out(const float* __restrict__ x,
                                              const float* __restrict__ wsm,
                                              float* __restrict__ out) {
    const int row = blockIdx.x;        // t*B + b
    const int t = row >> 4;
    const int c = threadIdx.x << 2;
    const int h = c >> 6;

    const float* __restrict__ wp = wsm + ((size_t)row * HH + h) * KK;
    float w[KK];
#pragma unroll
    for (int k = 0; k < KK; ++k) w[k] = wp[k];

    const int kmin = (t >= PADL) ? 0 : (PADL - t);
    float4 acc = make_float4(0.f, 0.f, 0.f, 0.f);
    for (int k = kmin; k < KK; ++k) {
        const float4 xv =
            *(const float4*)(x + ((size_t)row + (size_t)(k - PADL) * BB) * CC + c);
        acc.x += w[k] * xv.x;
        acc.y += w[k] * xv.y;
        acc.z += w[k] * xv.z;
        acc.w += w[k] * xv.w;
    }
    *(float4*)(out + (size_t)row * CC + c) = acc;
}

extern "C" void kernel_launch(void* const* d_in, const int* in_sizes, int n_in,
                              void* d_out, int out_size, void* d_ws, size_t ws_size,
                              hipStream_t stream) {
    const float* x = (const float*)d_in[0];   // (T, B, C)
    const float* W = (const float*)d_in[1];   // (H*K, C)
    float* out = (float*)d_out;                         // (T, B, C)
    float* dense = out + (size_t)TT * BB * CC;          // (B*H, T, T)
    float* wsm = (float*)d_ws;                          // (T, B, H, K) scratch

    k1_weights<<<(TT * BB) / 32, 256, 0, stream>>>(x, W, wsm);
    k2_dense<<<BB * HH * TT, 256, 0, stream>>>(wsm, dense);
    k3_out<<<TT * BB, 256, 0, stream>>>(x, wsm, out);
}

// Round 2
// 1310.931 us; speedup vs baseline: 1.1868x; 1.1868x over previous
//
#include <hip/hip_runtime.h>
#include <math.h>

#define TT 1024
#define BB 16
#define CC 1024
#define HH 16
#define KK 7
#define PADL 6
#define HK 112        // H*K
#define WSTRIDE 68    // LDS row stride in floats: 272 B (16B-aligned), 2-way bank alias only

// ---------------------------------------------------------------------------
// K1: logits = x @ W^T, band-masked softmax -> wsm[t,b,h,k].
// Thread layout: tx = tid&15 -> head (owns all 7 taps => thread-local softmax)
//                ty = tid>>4 -> row pair; block covers 32 (t,b) rows.
// W is staged per 64-channel chunk into LDS (coalesced global loads), then
// read back as ds_read_b128 at 2-way bank aliasing (free). This removes the
// 16-way L1 line-split the direct W loads suffered (16 heads x 28KB stride).
// grid = (T*B)/32 = 512 blocks, 256 threads.
// ---------------------------------------------------------------------------
__global__ __launch_bounds__(256) void k1_weights(const float* __restrict__ x,
                                                  const float* __restrict__ W,
                                                  float* __restrict__ wsm) {
    __shared__ float Wl[HK * WSTRIDE];   // 112*68*4 = 30.5 KB

    const int tid = threadIdx.x;
    const int tx = tid & 15;        // head
    const int ty = tid >> 4;        // 0..15
    const int row0 = blockIdx.x * 32 + ty * 2;   // (t*B + b) flat row

    const float* __restrict__ xr0 = x + (size_t)row0 * CC;
    const float* __restrict__ xr1 = xr0 + CC;

    float acc0[KK], acc1[KK];
#pragma unroll
    for (int k = 0; k < KK; ++k) { acc0[k] = 0.f; acc1[k] = 0.f; }

    for (int c0 = 0; c0 < CC; c0 += 64) {
        __syncthreads();   // previous chunk's reads done before overwrite
        // stage 112x64 chunk: flat i = j*1024 + tid*4 covers [0,7168) exactly
#pragma unroll
        for (int j = 0; j < 7; ++j) {
            const int i = j * 1024 + tid * 4;
            const int o = i >> 6;        // 0..111
            const int c = i & 63;        // 0..60, float4-aligned
            const float4 v = *(const float4*)(W + (size_t)o * CC + c0 + c);
            *(float4*)(&Wl[o * WSTRIDE + c]) = v;
        }
        __syncthreads();

        const float* __restrict__ Wb = &Wl[(tx * KK) * WSTRIDE];
#pragma unroll 4
        for (int c = 0; c < 64; c += 4) {
            const float4 xv0 = *(const float4*)(xr0 + c0 + c);
            const float4 xv1 = *(const float4*)(xr1 + c0 + c);
#pragma unroll
            for (int k = 0; k < KK; ++k) {
                const float4 wv = *(const float4*)(Wb + k * WSTRIDE + c);
                acc0[k] += xv0.x * wv.x + xv0.y * wv.y + xv0.z * wv.z + xv0.w * wv.w;
                acc1[k] += xv1.x * wv.x + xv1.y * wv.y + xv1.z * wv.z + xv1.w * wv.w;
            }
        }
    }

#pragma unroll
    for (int i = 0; i < 2; ++i) {
        const float* a = (i == 0) ? acc0 : acc1;
        const int row = row0 + i;
        const int t = row >> 4;                    // row = t*B + b
        const int kmin = (t >= PADL) ? 0 : (PADL - t);

        float m = -INFINITY;
#pragma unroll
        for (int k = 0; k < KK; ++k)
            if (k >= kmin) m = fmaxf(m, a[k]);

        float e[KK];
        float s = 0.f;
#pragma unroll
        for (int k = 0; k < KK; ++k) {
            if (k >= kmin) { e[k] = expf(a[k] - m); s += e[k]; }
            else           { e[k] = 0.f; }
        }
        const float inv = 1.f / s;
        float* __restrict__ wp = wsm + (((size_t)row * HH) + tx) * KK;
#pragma unroll
        for (int k = 0; k < KK; ++k) wp[k] = e[k] * inv;
    }
}

// ---------------------------------------------------------------------------
// K2: stream the full dense (B*H, T, T) band matrix. One block per
// (bh, 16-row t-chunk): 256 threads x 16 rows x float4 = 64 KB contiguous
// per block. 16x fewer waves than one-row-per-block; wave overhead amortized
// over 16 stores. grid = B*H*(T/16) = 16384 blocks.
// ---------------------------------------------------------------------------
__global__ __launch_bounds__(256) void k2_dense(const float* __restrict__ wsm,
                                                float* __restrict__ dense) {
    const int blk = blockIdx.x;        // bh*64 + tc
    const int bh = blk >> 6;
    const int tc = blk & 63;           // t-chunk
    const int b = bh >> 4;
    const int h = bh & 15;

    const int col = threadIdx.x << 2;
    const int t0 = tc * 16;

    float* __restrict__ drow = dense + ((size_t)bh * TT + t0) * TT + col;

#pragma unroll
    for (int i = 0; i < 16; ++i) {
        const int t = t0 + i;
        const int lo = t - PADL;       // may be negative
        float4 v = make_float4(0.f, 0.f, 0.f, 0.f);
        if (col + 3 >= lo && col <= t) {
            const float* __restrict__ wp =
                wsm + (((size_t)t * BB + b) * HH + h) * KK;
            float* pv = &v.x;
#pragma unroll
            for (int j = 0; j < 4; ++j) {
                const int cc = col + j;
                if (cc >= lo && cc <= t && cc >= 0) pv[j] = wp[cc - lo];
            }
        }
        *(float4*)drow = v;
        drow += TT;
    }
}

// ---------------------------------------------------------------------------
// K3: out[t,b,c] = sum_k wsm[t,b,h,k] * x[t+k-6, b, c],  h = c/64.
// One block per 4 (t,b) rows (same t), 256 threads x float4 over C.
// grid = T*B/4 = 4096 blocks.
// ---------------------------------------------------------------------------
__global__ __launch_bounds__(256) void k3_out(const float* __restrict__ x,
                                              const float* __restrict__ wsm,
                                              float* __restrict__ out) {
    const int r0 = blockIdx.x << 2;    // flat row = t*B + b; 4 rows share t
    const int t = r0 >> 4;
    const int c = threadIdx.x << 2;
    const int h = c >> 6;
    const int kmin = (t >= PADL) ? 0 : (PADL - t);

#pragma unroll
    for (int i = 0; i < 4; ++i) {
        const int row = r0 + i;
        const float* __restrict__ wp = wsm + ((size_t)row * HH + h) * KK;
        float w[KK];
#pragma unroll
        for (int k = 0; k < KK; ++k) w[k] = wp[k];

        float4 acc = make_float4(0.f, 0.f, 0.f, 0.f);
        for (int k = kmin; k < KK; ++k) {
            const float4 xv =
                *(const float4*)(x + ((size_t)row + (size_t)(k - PADL) * BB) * CC + c);
            acc.x += w[k] * xv.x;
            acc.y += w[k] * xv.y;
            acc.z += w[k] * xv.z;
            acc.w += w[k] * xv.w;
        }
        *(float4*)(out + (size_t)row * CC + c) = acc;
    }
}

extern "C" void kernel_launch(void* const* d_in, const int* in_sizes, int n_in,
                              void* d_out, int out_size, void* d_ws, size_t ws_size,
                              hipStream_t stream) {
    const float* x = (const float*)d_in[0];   // (T, B, C)
    const float* W = (const float*)d_in[1];   // (H*K, C)
    float* out = (float*)d_out;                         // (T, B, C)
    float* dense = out + (size_t)TT * BB * CC;          // (B*H, T, T)
    float* wsm = (float*)d_ws;                          // (T, B, H, K) scratch

    k1_weights<<<(TT * BB) / 32, 256, 0, stream>>>(x, W, wsm);
    k2_dense<<<BB * HH * (TT / 16), 256, 0, stream>>>(wsm, dense);
    k3_out<<<(TT * BB) / 4, 256, 0, stream>>>(x, wsm, out);
}